// Round 8
// baseline (108.433 us; speedup 1.0000x reference)
//
#include <hip/hip_runtime.h>
#include <hip/hip_bf16.h>

#define N_NODES 65536
#define N_EDGES (N_NODES * 7)
#define NSEG    (N_NODES * 7)          // 458752
#define CAP     12
#define ZROW    65536                  // index of the all-zero row in xb

typedef short short8 __attribute__((ext_vector_type(8)));
typedef float f32x4  __attribute__((ext_vector_type(4)));

// f32 -> bf16 via hardware cvt (compiler emits v_cvt_pk_bf16_f32 for pairs)
__device__ __forceinline__ unsigned short f2bf(float f) {
    return __builtin_bit_cast(unsigned short, (__bf16)f);
}
__device__ __forceinline__ unsigned pack2(float lo, float hi) {
    return (unsigned)f2bf(lo) | ((unsigned)f2bf(hi) << 16);
}
// bf16 pair unpack from dword
__device__ __forceinline__ float bflo(unsigned d) { return __uint_as_float(d << 16); }
__device__ __forceinline__ float bfhi(unsigned d) { return __uint_as_float(d & 0xffff0000u); }

// ---------------- fused prep: edge scatter + x->bf16 + W->B-frag ----------------
// seg32[seg] = cnt(7b at bit 0) | typecount_u(5b at bit 7+5u). Pre-zeroed by memset.
__global__ __launch_bounds__(256) void k_big(const float* __restrict__ x,
                                             const int* __restrict__ eidx,
                                             const int* __restrict__ etype,
                                             const int* __restrict__ ntype,
                                             const float* __restrict__ W,
                                             unsigned short* __restrict__ xb,
                                             unsigned short* __restrict__ wb,
                                             unsigned* __restrict__ seg32,
                                             unsigned short* __restrict__ scol) {
    int i = blockIdx.x * 256 + threadIdx.x;     // grid 4096*256 = 1048576

    // edge scatter (issue first: its random loads overlap the streaming below)
    if (i < N_EDGES) {
        int t = etype[i];
        if (t < 6) {                    // type-6 slot overwritten by self-loop
            int r = eidx[i];
            int c = eidx[N_EDGES + i];
            int u = ntype[c];
            unsigned seg = (unsigned)r * 7u + (unsigned)t;
            unsigned inc = 1u | (1u << (7 + 5 * u));
            unsigned old = atomicAdd(&seg32[seg], inc);
            unsigned slot = old & 0x7fu;
            if (slot < CAP) scol[seg * CAP + slot] = (unsigned short)c;
        }
    }

    // x -> bf16 rows
    {
        int row = i >> 4, mm = i & 15;
        const f32x4* p = reinterpret_cast<const f32x4*>(x + (size_t)row * 128 + mm * 8);
        f32x4 v0 = p[0], v1 = p[1];
        uint4 w;
        w.x = pack2(v0[0], v0[1]); w.y = pack2(v0[2], v0[3]);
        w.z = pack2(v1[0], v1[1]); w.w = pack2(v1[2], v1[3]);
        reinterpret_cast<uint4*>(xb)[i] = w;
    }

    // zero row (gather fallback target)
    if (i < 16) reinterpret_cast<uint4*>(xb + (size_t)ZROW * 128)[i] = (uint4){0u, 0u, 0u, 0u};

    // W -> bf16 B-fragment order
    if (i < 143360) {
        int j    = i & 7;
        int lane = (i >> 3) & 63;
        int cb   = (i >> 9) & 7;
        int tkc  = i >> 12;
        int kc   = tkc % 5;
        int t    = tkc / 5;
        int k = kc * 32 + ((lane >> 4) << 3) + j;
        int c = cb * 16 + (lane & 15);
        float v = (k < 133) ? W[(t * 133 + k) * 128 + c] : 0.0f;
        wb[i] = f2bf(v);
    }
}

// ---------------- main fused kernel ----------------
// Two-phase schedule, sA = 4 tiles (43 KB) -> 3 blocks/CU (24 waves).
// Phase 1: build {t0,t1,t2,self}, issue t3-5 e0/e1 loads, barrier, marathon-1.
// Phase 2: rebuild slots 0-2 with {t3,t4,t5}, barrier, marathon-2.
__global__ __launch_bounds__(512, 6) void k_main(const unsigned short* __restrict__ xb,
                                                 const int* __restrict__ ntype,
                                                 const unsigned* __restrict__ seg32,
                                                 const unsigned short* __restrict__ scol,
                                                 const unsigned short* __restrict__ wb,
                                                 float* __restrict__ out) {
    __shared__ unsigned short sA[4 * 32 * 168];   // 43008 B

    const int tid  = threadIdx.x;
    const int lane = tid & 63;
    const int wid  = tid >> 6;
    const int n0   = blockIdx.x * 32;
    const int r    = tid >> 4;      // row 0..31
    const int m    = tid & 15;      // 8-channel chunk
    const int n    = n0 + r;

    // zero pad: dwords 68..79 of each of the 128 rows (shorts 136..159)
    #pragma unroll
    for (int k2 = 0; k2 < 3; ++k2) {
        int i = tid + k2 * 512;
        int row = i / 12, j = i - row * 12;
        reinterpret_cast<unsigned*>(sA)[row * 84 + 68 + j] = 0u;
    }

    // all per-type packed counters + first-4 edge cols (L1-broadcast in 16-lane group)
    unsigned sv[6], c_t[6];
    uint2 q2[6];
    #pragma unroll
    for (int t = 0; t < 6; ++t) {
        sv[t]  = seg32[n * 7 + t];
        c_t[t] = sv[t] & 0x7fu;
        q2[t]  = *reinterpret_cast<const uint2*>(scol + ((size_t)n * 7 + t) * CAP);
    }

    // issue phase-1 e0/e1 loads (t0..2) + self row
    short8 xA[3], xB[3], xS;
    #pragma unroll
    for (int t = 0; t < 3; ++t) {
        unsigned cA = (c_t[t] >= 1u) ? (q2[t].x & 0xffffu) : (unsigned)ZROW;
        unsigned cB = (c_t[t] >= 2u) ? (q2[t].x >> 16)     : (unsigned)ZROW;
        xA[t] = *reinterpret_cast<const short8*>(xb + (size_t)cA * 128 + m * 8);
        xB[t] = *reinterpret_cast<const short8*>(xb + (size_t)cB * 128 + m * 8);
    }
    xS = *reinterpret_cast<const short8*>(xb + (size_t)n * 128 + m * 8);
    const int ntS = ntype[n];

    // ---- tile builder (one (row,t) segment, this thread's 8 channels) ----
    auto build_tile = [&](int t, int tile, short8 xa, short8 xbv) {
        const unsigned cntv = c_t[t];
        const float inv = (cntv > 1u) ? __builtin_amdgcn_rcpf((float)cntv) : 1.0f;
        uint4 a4 = *reinterpret_cast<const uint4*>(&xa);
        uint4 w;
        if (cntv <= 1u) {
            w = a4;                      // cnt=0 -> ZROW zeros; cnt=1 -> exact copy
        } else {
            uint4 b4 = *reinterpret_cast<const uint4*>(&xbv);
            float a[8];
            a[0] = bflo(a4.x) + bflo(b4.x); a[1] = bfhi(a4.x) + bfhi(b4.x);
            a[2] = bflo(a4.y) + bflo(b4.y); a[3] = bfhi(a4.y) + bfhi(b4.y);
            a[4] = bflo(a4.z) + bflo(b4.z); a[5] = bfhi(a4.z) + bfhi(b4.z);
            a[6] = bflo(a4.w) + bflo(b4.w); a[7] = bfhi(a4.w) + bfhi(b4.w);
            if (cntv >= 3u) {            // rare tail (~8% of segments)
                const unsigned ce = (cntv < (unsigned)CAP) ? cntv : (unsigned)CAP;
                {
                    unsigned c2 = q2[t].y & 0xffffu;
                    short8 v = *reinterpret_cast<const short8*>(xb + (size_t)c2 * 128 + m * 8);
                    uint4 v4 = *reinterpret_cast<const uint4*>(&v);
                    a[0] += bflo(v4.x); a[1] += bfhi(v4.x);
                    a[2] += bflo(v4.y); a[3] += bfhi(v4.y);
                    a[4] += bflo(v4.z); a[5] += bfhi(v4.z);
                    a[6] += bflo(v4.w); a[7] += bfhi(v4.w);
                }
                if (ce >= 4u) {
                    unsigned c3 = q2[t].y >> 16;
                    short8 v = *reinterpret_cast<const short8*>(xb + (size_t)c3 * 128 + m * 8);
                    uint4 v4 = *reinterpret_cast<const uint4*>(&v);
                    a[0] += bflo(v4.x); a[1] += bfhi(v4.x);
                    a[2] += bflo(v4.y); a[3] += bfhi(v4.y);
                    a[4] += bflo(v4.z); a[5] += bfhi(v4.z);
                    a[6] += bflo(v4.w); a[7] += bfhi(v4.w);
                    const size_t segbase = ((size_t)n * 7 + t) * CAP;
                    for (unsigned e = 4; e < ce; ++e) {
                        unsigned c = scol[segbase + e];
                        short8 ve = *reinterpret_cast<const short8*>(xb + (size_t)c * 128 + m * 8);
                        uint4 v4e = *reinterpret_cast<const uint4*>(&ve);
                        a[0] += bflo(v4e.x); a[1] += bfhi(v4e.x);
                        a[2] += bflo(v4e.y); a[3] += bfhi(v4e.y);
                        a[4] += bflo(v4e.z); a[5] += bfhi(v4e.z);
                        a[6] += bflo(v4e.w); a[7] += bfhi(v4e.w);
                    }
                }
            }
            w.x = pack2(a[0] * inv, a[1] * inv); w.y = pack2(a[2] * inv, a[3] * inv);
            w.z = pack2(a[4] * inv, a[5] * inv); w.w = pack2(a[6] * inv, a[7] * inv);
        }
        *reinterpret_cast<uint4*>(sA + (tile * 32 + r) * 168 + m * 8) = w;
        if (m < 4) {
            int i0 = 2 * m, i1 = 2 * m + 1;
            float g0 = (i0 < 5) ? (float)((sv[t] >> (7 + 5 * i0)) & 31u) : 0.f;
            float g1 = (i1 < 5) ? (float)((sv[t] >> (7 + 5 * i1)) & 31u) : 0.f;
            reinterpret_cast<unsigned*>(sA)[(tile * 32 + r) * 84 + 64 + m] =
                pack2(g0 * inv, g1 * inv);
        }
    };

    // ---- phase-1 build: tiles {t0,t1,t2,self} ----
    #pragma unroll
    for (int t = 0; t < 3; ++t) build_tile(t, t, xA[t], xB[t]);
    *reinterpret_cast<uint4*>(sA + (3 * 32 + r) * 168 + m * 8) =
        *reinterpret_cast<const uint4*>(&xS);
    if (m < 4) {
        float g0 = (ntS == 2 * m) ? 1.f : 0.f;
        float g1 = (ntS == 2 * m + 1) ? 1.f : 0.f;
        reinterpret_cast<unsigned*>(sA)[(3 * 32 + r) * 84 + 64 + m] = pack2(g0, g1);
    }

    // issue phase-2 e0/e1 loads (t3..5) -- latency hides under marathon-1
    short8 xA2[3], xB2[3];
    #pragma unroll
    for (int t = 3; t < 6; ++t) {
        unsigned cA = (c_t[t] >= 1u) ? (q2[t].x & 0xffffu) : (unsigned)ZROW;
        unsigned cB = (c_t[t] >= 2u) ? (q2[t].x >> 16)     : (unsigned)ZROW;
        xA2[t - 3] = *reinterpret_cast<const short8*>(xb + (size_t)cA * 128 + m * 8);
        xB2[t - 3] = *reinterpret_cast<const short8*>(xb + (size_t)cB * 128 + m * 8);
    }

    __syncthreads();

    // ---- marathon 1: tiles 0..3, B types {0,1,2,6} ----
    f32x4 acc0 = {0.f, 0.f, 0.f, 0.f};
    f32x4 acc1 = {0.f, 0.f, 0.f, 0.f};
    const int ar = lane & 15;
    const int hi = (lane >> 4) << 3;

    #pragma unroll
    for (int i = 0; i < 4; ++i) {
        const int bt = (i == 3) ? 6 : i;
        short8 bv[5];
        #pragma unroll
        for (int kc = 0; kc < 5; ++kc)
            bv[kc] = *reinterpret_cast<const short8*>(
                wb + ((((bt * 5 + kc) * 8 + wid) << 6) + lane) * 8);
        #pragma unroll
        for (int kc = 0; kc < 5; ++kc) {
            short8 a0 = *reinterpret_cast<const short8*>(
                sA + (i * 32 + ar) * 168 + kc * 32 + hi);
            short8 a1 = *reinterpret_cast<const short8*>(
                sA + (i * 32 + 16 + ar) * 168 + kc * 32 + hi);
            acc0 = __builtin_amdgcn_mfma_f32_16x16x32_bf16(a0, bv[kc], acc0, 0, 0, 0);
            acc1 = __builtin_amdgcn_mfma_f32_16x16x32_bf16(a1, bv[kc], acc1, 0, 0, 0);
        }
    }

    __syncthreads();   // marathon-1 reads done before overwrite

    // ---- phase-2 build: tiles 0..2 = {t3,t4,t5} ----
    #pragma unroll
    for (int t = 0; t < 3; ++t) build_tile(t + 3, t, xA2[t], xB2[t]);

    __syncthreads();

    // ---- marathon 2: tiles 0..2, B types {3,4,5} ----
    #pragma unroll
    for (int i = 0; i < 3; ++i) {
        const int bt = 3 + i;
        short8 bv[5];
        #pragma unroll
        for (int kc = 0; kc < 5; ++kc)
            bv[kc] = *reinterpret_cast<const short8*>(
                wb + ((((bt * 5 + kc) * 8 + wid) << 6) + lane) * 8);
        #pragma unroll
        for (int kc = 0; kc < 5; ++kc) {
            short8 a0 = *reinterpret_cast<const short8*>(
                sA + (i * 32 + ar) * 168 + kc * 32 + hi);
            short8 a1 = *reinterpret_cast<const short8*>(
                sA + (i * 32 + 16 + ar) * 168 + kc * 32 + hi);
            acc0 = __builtin_amdgcn_mfma_f32_16x16x32_bf16(a0, bv[kc], acc0, 0, 0, 0);
            acc1 = __builtin_amdgcn_mfma_f32_16x16x32_bf16(a1, bv[kc], acc1, 0, 0, 0);
        }
    }

    // epilogue: C/D layout col = lane&15, row = (lane>>4)*4 + reg
    const int orow = n0 + ((lane >> 4) << 2);
    const int ocol = (wid << 4) + (lane & 15);
    #pragma unroll
    for (int rr = 0; rr < 4; ++rr) {
        out[(size_t)(orow + rr) * 128 + ocol]      = acc0[rr];
        out[(size_t)(orow + 16 + rr) * 128 + ocol] = acc1[rr];
    }
}

// ---------------- launch ----------------

extern "C" void kernel_launch(void* const* d_in, const int* in_sizes, int n_in,
                              void* d_out, int out_size, void* d_ws, size_t ws_size,
                              hipStream_t stream) {
    const float* x     = (const float*)d_in[0];
    const int*   eidx  = (const int*)d_in[1];
    const int*   etype = (const int*)d_in[2];
    const int*   ntype = (const int*)d_in[3];
    const float* W     = (const float*)d_in[4];
    float* out = (float*)d_out;

    // ws: xb (65537 rows) 16777472 | wb 286720 | seg32 1835008 | scol 11010048
    unsigned short* xb    = (unsigned short*)d_ws;
    unsigned short* wb    = (unsigned short*)((char*)d_ws + 16777472);
    unsigned*       seg32 = (unsigned*)((char*)d_ws + 17064192);
    unsigned short* scol  = (unsigned short*)((char*)d_ws + 18899200);

    hipMemsetAsync(seg32, 0, NSEG * sizeof(unsigned), stream);
    k_big <<<4096,         256, 0, stream>>>(x, eidx, etype, ntype, W, xb, wb, seg32, scol);
    k_main<<<N_NODES / 32, 512, 0, stream>>>(xb, ntype, seg32, scol, wb, out);
}

// Round 9
// 79.627 us; speedup vs baseline: 1.3618x; 1.3618x over previous
//
#include <hip/hip_runtime.h>
#include <hip/hip_bf16.h>

#define N_NODES 65536
#define N_EDGES (N_NODES * 7)
#define NSEG    (N_NODES * 7)          // 458752
#define CAP     12
#define ZROW    65536                  // index of the all-zero row in xb

typedef short short8 __attribute__((ext_vector_type(8)));
typedef float f32x4  __attribute__((ext_vector_type(4)));

// f32 -> bf16 via hardware cvt (compiler emits v_cvt_pk_bf16_f32 for pairs)
__device__ __forceinline__ unsigned short f2bf(float f) {
    return __builtin_bit_cast(unsigned short, (__bf16)f);
}
__device__ __forceinline__ unsigned pack2(float lo, float hi) {
    return (unsigned)f2bf(lo) | ((unsigned)f2bf(hi) << 16);
}
// bf16 pair unpack from dword
__device__ __forceinline__ float bflo(unsigned d) { return __uint_as_float(d << 16); }
__device__ __forceinline__ float bfhi(unsigned d) { return __uint_as_float(d & 0xffff0000u); }

// ---------------- fused prep: edge scatter + x->bf16 + W->B-frag ----------------
// seg32[seg] = cnt(7b at bit 0) | typecount_u(5b at bit 7+5u). Pre-zeroed by memset.
__global__ __launch_bounds__(256) void k_big(const float* __restrict__ x,
                                             const int* __restrict__ eidx,
                                             const int* __restrict__ etype,
                                             const int* __restrict__ ntype,
                                             const float* __restrict__ W,
                                             unsigned short* __restrict__ xb,
                                             unsigned short* __restrict__ wb,
                                             unsigned* __restrict__ seg32,
                                             unsigned short* __restrict__ scol) {
    int i = blockIdx.x * 256 + threadIdx.x;     // grid 4096*256 = 1048576

    // edge scatter (issue first: its random loads overlap the streaming below)
    if (i < N_EDGES) {
        int t = etype[i];
        if (t < 6) {                    // type-6 slot overwritten by self-loop
            int r = eidx[i];
            int c = eidx[N_EDGES + i];
            int u = ntype[c];
            unsigned seg = (unsigned)r * 7u + (unsigned)t;
            unsigned inc = 1u | (1u << (7 + 5 * u));
            unsigned old = atomicAdd(&seg32[seg], inc);
            unsigned slot = old & 0x7fu;
            if (slot < CAP) scol[seg * CAP + slot] = (unsigned short)c;
        }
    }

    // x -> bf16 rows
    {
        int row = i >> 4, mm = i & 15;
        const f32x4* p = reinterpret_cast<const f32x4*>(x + (size_t)row * 128 + mm * 8);
        f32x4 v0 = p[0], v1 = p[1];
        uint4 w;
        w.x = pack2(v0[0], v0[1]); w.y = pack2(v0[2], v0[3]);
        w.z = pack2(v1[0], v1[1]); w.w = pack2(v1[2], v1[3]);
        reinterpret_cast<uint4*>(xb)[i] = w;
    }

    // zero row (gather fallback target)
    if (i < 16) reinterpret_cast<uint4*>(xb + (size_t)ZROW * 128)[i] = (uint4){0u, 0u, 0u, 0u};

    // W -> bf16 B-fragment order
    if (i < 143360) {
        int j    = i & 7;
        int lane = (i >> 3) & 63;
        int cb   = (i >> 9) & 7;
        int tkc  = i >> 12;
        int kc   = tkc % 5;
        int t    = tkc / 5;
        int k = kc * 32 + ((lane >> 4) << 3) + j;
        int c = cb * 16 + (lane & 15);
        float v = (k < 133) ? W[(t * 133 + k) * 128 + c] : 0.0f;
        wb[i] = f2bf(v);
    }
}

// ---------------- main fused kernel ----------------
// Two-phase schedule, sA = 4 tiles (43 KB) -> 3 blocks/CU (24 waves).
// Phase 1: build {t0,t1,t2,self}, barrier, marathon-1 (B types {0,1,2,6}).
// Phase 2: issue t3-5 loads, rebuild slots 0-2, barrier, marathon-2 ({3,4,5}).
// NO registers held across marathon-1 (R8's spill fix): phase-2 gather
// latency is hidden by the other two resident blocks' marathons.
__global__ __launch_bounds__(512, 6) void k_main(const unsigned short* __restrict__ xb,
                                                 const int* __restrict__ ntype,
                                                 const unsigned* __restrict__ seg32,
                                                 const unsigned short* __restrict__ scol,
                                                 const unsigned short* __restrict__ wb,
                                                 float* __restrict__ out) {
    __shared__ unsigned short sA[4 * 32 * 168];   // 43008 B

    const int tid  = threadIdx.x;
    const int lane = tid & 63;
    const int wid  = tid >> 6;
    const int n0   = blockIdx.x * 32;
    const int r    = tid >> 4;      // row 0..31
    const int m    = tid & 15;      // 8-channel chunk
    const int n    = n0 + r;

    // zero pad: dwords 68..79 of each of the 128 rows (shorts 136..159)
    #pragma unroll
    for (int k2 = 0; k2 < 3; ++k2) {
        int i = tid + k2 * 512;
        int row = i / 12, j = i - row * 12;
        reinterpret_cast<unsigned*>(sA)[row * 84 + 68 + j] = 0u;
    }

    // all per-type packed counters + first-4 edge cols (L1-broadcast in 16-lane group)
    unsigned sv[6], c_t[6];
    uint2 q2[6];
    #pragma unroll
    for (int t = 0; t < 6; ++t) {
        sv[t]  = seg32[n * 7 + t];
        c_t[t] = sv[t] & 0x7fu;
        q2[t]  = *reinterpret_cast<const uint2*>(scol + ((size_t)n * 7 + t) * CAP);
    }

    // ---- tile builder (one (row,t) segment, this thread's 8 channels) ----
    auto build_tile = [&](int t, int tile, short8 xa, short8 xbv) {
        const unsigned cntv = c_t[t];
        const float inv = (cntv > 1u) ? __builtin_amdgcn_rcpf((float)cntv) : 1.0f;
        uint4 a4 = *reinterpret_cast<const uint4*>(&xa);
        uint4 w;
        if (cntv <= 1u) {
            w = a4;                      // cnt=0 -> ZROW zeros; cnt=1 -> exact copy
        } else {
            uint4 b4 = *reinterpret_cast<const uint4*>(&xbv);
            float a[8];
            a[0] = bflo(a4.x) + bflo(b4.x); a[1] = bfhi(a4.x) + bfhi(b4.x);
            a[2] = bflo(a4.y) + bflo(b4.y); a[3] = bfhi(a4.y) + bfhi(b4.y);
            a[4] = bflo(a4.z) + bflo(b4.z); a[5] = bfhi(a4.z) + bfhi(b4.z);
            a[6] = bflo(a4.w) + bflo(b4.w); a[7] = bfhi(a4.w) + bfhi(b4.w);
            if (cntv >= 3u) {            // rare tail (~8% of segments)
                const unsigned ce = (cntv < (unsigned)CAP) ? cntv : (unsigned)CAP;
                {
                    unsigned c2 = q2[t].y & 0xffffu;
                    short8 v = *reinterpret_cast<const short8*>(xb + (size_t)c2 * 128 + m * 8);
                    uint4 v4 = *reinterpret_cast<const uint4*>(&v);
                    a[0] += bflo(v4.x); a[1] += bfhi(v4.x);
                    a[2] += bflo(v4.y); a[3] += bfhi(v4.y);
                    a[4] += bflo(v4.z); a[5] += bfhi(v4.z);
                    a[6] += bflo(v4.w); a[7] += bfhi(v4.w);
                }
                if (ce >= 4u) {
                    unsigned c3 = q2[t].y >> 16;
                    short8 v = *reinterpret_cast<const short8*>(xb + (size_t)c3 * 128 + m * 8);
                    uint4 v4 = *reinterpret_cast<const uint4*>(&v);
                    a[0] += bflo(v4.x); a[1] += bfhi(v4.x);
                    a[2] += bflo(v4.y); a[3] += bfhi(v4.y);
                    a[4] += bflo(v4.z); a[5] += bfhi(v4.z);
                    a[6] += bflo(v4.w); a[7] += bfhi(v4.w);
                    const size_t segbase = ((size_t)n * 7 + t) * CAP;
                    for (unsigned e = 4; e < ce; ++e) {
                        unsigned c = scol[segbase + e];
                        short8 ve = *reinterpret_cast<const short8*>(xb + (size_t)c * 128 + m * 8);
                        uint4 v4e = *reinterpret_cast<const uint4*>(&ve);
                        a[0] += bflo(v4e.x); a[1] += bfhi(v4e.x);
                        a[2] += bflo(v4e.y); a[3] += bfhi(v4e.y);
                        a[4] += bflo(v4e.z); a[5] += bfhi(v4e.z);
                        a[6] += bflo(v4e.w); a[7] += bfhi(v4e.w);
                    }
                }
            }
            w.x = pack2(a[0] * inv, a[1] * inv); w.y = pack2(a[2] * inv, a[3] * inv);
            w.z = pack2(a[4] * inv, a[5] * inv); w.w = pack2(a[6] * inv, a[7] * inv);
        }
        *reinterpret_cast<uint4*>(sA + (tile * 32 + r) * 168 + m * 8) = w;
        if (m < 4) {
            int i0 = 2 * m, i1 = 2 * m + 1;
            float g0 = (i0 < 5) ? (float)((sv[t] >> (7 + 5 * i0)) & 31u) : 0.f;
            float g1 = (i1 < 5) ? (float)((sv[t] >> (7 + 5 * i1)) & 31u) : 0.f;
            reinterpret_cast<unsigned*>(sA)[(tile * 32 + r) * 84 + 64 + m] =
                pack2(g0 * inv, g1 * inv);
        }
    };

    // ---- phase-1: issue t0..2 e0/e1 + self loads, then build ----
    {
        short8 xA[3], xB[3], xS;
        #pragma unroll
        for (int t = 0; t < 3; ++t) {
            unsigned cA = (c_t[t] >= 1u) ? (q2[t].x & 0xffffu) : (unsigned)ZROW;
            unsigned cB = (c_t[t] >= 2u) ? (q2[t].x >> 16)     : (unsigned)ZROW;
            xA[t] = *reinterpret_cast<const short8*>(xb + (size_t)cA * 128 + m * 8);
            xB[t] = *reinterpret_cast<const short8*>(xb + (size_t)cB * 128 + m * 8);
        }
        xS = *reinterpret_cast<const short8*>(xb + (size_t)n * 128 + m * 8);
        const int ntS = ntype[n];

        #pragma unroll
        for (int t = 0; t < 3; ++t) build_tile(t, t, xA[t], xB[t]);
        *reinterpret_cast<uint4*>(sA + (3 * 32 + r) * 168 + m * 8) =
            *reinterpret_cast<const uint4*>(&xS);
        if (m < 4) {
            float g0 = (ntS == 2 * m) ? 1.f : 0.f;
            float g1 = (ntS == 2 * m + 1) ? 1.f : 0.f;
            reinterpret_cast<unsigned*>(sA)[(3 * 32 + r) * 84 + 64 + m] = pack2(g0, g1);
        }
    }

    __syncthreads();

    // ---- marathon 1: tiles 0..3, B types {0,1,2,6} ----
    f32x4 acc0 = {0.f, 0.f, 0.f, 0.f};
    f32x4 acc1 = {0.f, 0.f, 0.f, 0.f};
    const int ar = lane & 15;
    const int hi = (lane >> 4) << 3;

    #pragma unroll
    for (int i = 0; i < 4; ++i) {
        const int bt = (i == 3) ? 6 : i;
        short8 bv[5];
        #pragma unroll
        for (int kc = 0; kc < 5; ++kc)
            bv[kc] = *reinterpret_cast<const short8*>(
                wb + ((((bt * 5 + kc) * 8 + wid) << 6) + lane) * 8);
        #pragma unroll
        for (int kc = 0; kc < 5; ++kc) {
            short8 a0 = *reinterpret_cast<const short8*>(
                sA + (i * 32 + ar) * 168 + kc * 32 + hi);
            short8 a1 = *reinterpret_cast<const short8*>(
                sA + (i * 32 + 16 + ar) * 168 + kc * 32 + hi);
            acc0 = __builtin_amdgcn_mfma_f32_16x16x32_bf16(a0, bv[kc], acc0, 0, 0, 0);
            acc1 = __builtin_amdgcn_mfma_f32_16x16x32_bf16(a1, bv[kc], acc1, 0, 0, 0);
        }
    }

    __syncthreads();   // marathon-1 reads done before overwrite

    // ---- phase-2: issue all t3..5 loads up-front (MLP), then build ----
    {
        short8 xA2[3], xB2[3];
        #pragma unroll
        for (int t = 3; t < 6; ++t) {
            unsigned cA = (c_t[t] >= 1u) ? (q2[t].x & 0xffffu) : (unsigned)ZROW;
            unsigned cB = (c_t[t] >= 2u) ? (q2[t].x >> 16)     : (unsigned)ZROW;
            xA2[t - 3] = *reinterpret_cast<const short8*>(xb + (size_t)cA * 128 + m * 8);
            xB2[t - 3] = *reinterpret_cast<const short8*>(xb + (size_t)cB * 128 + m * 8);
        }
        #pragma unroll
        for (int t = 0; t < 3; ++t) build_tile(t + 3, t, xA2[t], xB2[t]);
    }

    __syncthreads();

    // ---- marathon 2: tiles 0..2, B types {3,4,5} ----
    #pragma unroll
    for (int i = 0; i < 3; ++i) {
        const int bt = 3 + i;
        short8 bv[5];
        #pragma unroll
        for (int kc = 0; kc < 5; ++kc)
            bv[kc] = *reinterpret_cast<const short8*>(
                wb + ((((bt * 5 + kc) * 8 + wid) << 6) + lane) * 8);
        #pragma unroll
        for (int kc = 0; kc < 5; ++kc) {
            short8 a0 = *reinterpret_cast<const short8*>(
                sA + (i * 32 + ar) * 168 + kc * 32 + hi);
            short8 a1 = *reinterpret_cast<const short8*>(
                sA + (i * 32 + 16 + ar) * 168 + kc * 32 + hi);
            acc0 = __builtin_amdgcn_mfma_f32_16x16x32_bf16(a0, bv[kc], acc0, 0, 0, 0);
            acc1 = __builtin_amdgcn_mfma_f32_16x16x32_bf16(a1, bv[kc], acc1, 0, 0, 0);
        }
    }

    // epilogue: C/D layout col = lane&15, row = (lane>>4)*4 + reg
    const int orow = n0 + ((lane >> 4) << 2);
    const int ocol = (wid << 4) + (lane & 15);
    #pragma unroll
    for (int rr = 0; rr < 4; ++rr) {
        out[(size_t)(orow + rr) * 128 + ocol]      = acc0[rr];
        out[(size_t)(orow + 16 + rr) * 128 + ocol] = acc1[rr];
    }
}

// ---------------- launch ----------------

extern "C" void kernel_launch(void* const* d_in, const int* in_sizes, int n_in,
                              void* d_out, int out_size, void* d_ws, size_t ws_size,
                              hipStream_t stream) {
    const float* x     = (const float*)d_in[0];
    const int*   eidx  = (const int*)d_in[1];
    const int*   etype = (const int*)d_in[2];
    const int*   ntype = (const int*)d_in[3];
    const float* W     = (const float*)d_in[4];
    float* out = (float*)d_out;

    // ws: xb (65537 rows) 16777472 | wb 286720 | seg32 1835008 | scol 11010048
    unsigned short* xb    = (unsigned short*)d_ws;
    unsigned short* wb    = (unsigned short*)((char*)d_ws + 16777472);
    unsigned*       seg32 = (unsigned*)((char*)d_ws + 17064192);
    unsigned short* scol  = (unsigned short*)((char*)d_ws + 18899200);

    hipMemsetAsync(seg32, 0, NSEG * sizeof(unsigned), stream);
    k_big <<<4096,         256, 0, stream>>>(x, eidx, etype, ntype, W, xb, wb, seg32, scol);
    k_main<<<N_NODES / 32, 512, 0, stream>>>(xb, ntype, seg32, scol, wb, out);
}